// Round 1
// baseline (277.151 us; speedup 1.0000x reference)
//
#include <hip/hip_runtime.h>
#include <hip/hip_bf16.h>

typedef __bf16 bf16x8 __attribute__((ext_vector_type(8)));
typedef float f32x4 __attribute__((ext_vector_type(4)));
typedef unsigned short u16;
typedef unsigned int u32;

// B=4, S=2048, D=1024, H=16, Dh=64
#define SB 4
#define SS 2048
#define SD 1024
#define SH 16
#define SDH 64

__device__ __forceinline__ u16 f2bf(float f) {
  union { float f; u32 u; } x; x.f = f;
  u32 r = (x.u + 0x7FFFu + ((x.u >> 16) & 1u)) >> 16;
  return (u16)r;
}

__device__ __forceinline__ void gl_lds16(const void* g, void* l) {
  __builtin_amdgcn_global_load_lds(
      (__attribute__((address_space(1))) void*)g,
      (__attribute__((address_space(3))) void*)l, 16, 0, 0);
}

// ---------------- cast fp32 -> bf16, 8 elems/thread ----------------
__global__ void cast_bf16_kernel(const float* __restrict__ in,
                                 u32* __restrict__ out, int n8) {
  int i = blockIdx.x * blockDim.x + threadIdx.x;
  if (i >= n8) return;
  const float4* inp = (const float4*)in;
  float4 a = inp[2 * i], b = inp[2 * i + 1];
  uint4 o;
  o.x = (u32)f2bf(a.x) | ((u32)f2bf(a.y) << 16);
  o.y = (u32)f2bf(a.z) | ((u32)f2bf(a.w) << 16);
  o.z = (u32)f2bf(b.x) | ((u32)f2bf(b.y) << 16);
  o.w = (u32)f2bf(b.z) | ((u32)f2bf(b.w) << 16);
  ((uint4*)out)[i] = o;
}

// ---------------- transpose + cast weight: Wt[n][k] = W[k][n] ------
__global__ void transpose_cast_kernel(const float* __restrict__ W,
                                      u16* __restrict__ Wt) {
  __shared__ float t[32][33];
  int bx = blockIdx.x, by = blockIdx.y;
  int tx = threadIdx.x, ty = threadIdx.y;  // 32 x 8
#pragma unroll
  for (int j = 0; j < 32; j += 8)
    t[ty + j][tx] = W[(size_t)(by * 32 + ty + j) * SD + bx * 32 + tx];
  __syncthreads();
#pragma unroll
  for (int j = 0; j < 32; j += 8)
    Wt[(size_t)(bx * 32 + ty + j) * SD + by * 32 + tx] = f2bf(t[tx][ty + j]);
}

// ---------------- GEMM: C[m][n] = sum_k A[m][k]*Bt[n][k] (+bias) ---
// 128x128 tile, BK=32, 256 thr = 4 waves (2x2), wave tile 64x64.
// MODE 0: out bf16 Qh[b][h][s][dh], scale 1/8   (bias[n])
// MODE 1: out bf16 Kh[b][h][s][dh]              (bias[n])
// MODE 2: out bf16 Vt[b][h][dh][s]  (A=WvT M=1024, Bt=vb N=8192, bias[m])
// MODE 3: out fp32 [m][n] (+bias[n])
template <int MODE>
__global__ __launch_bounds__(256, 2)
void gemm_bt(const u16* __restrict__ A, const u16* __restrict__ Bt,
             const float* __restrict__ bias, void* __restrict__ Out,
             int M, int N, int K) {
  __shared__ u16 Asl[128 * 32];
  __shared__ u16 Bsl[128 * 32];
  const int ntile = N >> 7;
  int bid = blockIdx.x;
  int m0 = (bid / ntile) * 128, n0 = (bid % ntile) * 128;
  int tid = threadIdx.x;
  int lane = tid & 63, wv = tid >> 6;
  int wr = wv >> 1, wc = wv & 1;

  f32x4 acc[4][4] = {};

  for (int k0 = 0; k0 < K; k0 += 32) {
#pragma unroll
    for (int it = 0; it < 2; ++it) {
      int c = tid + it * 256;            // 512 chunks of 16B per tile
      int row = c >> 2, sl = c & 3;      // 4 x 16B per 64B row
      gl_lds16(A + (size_t)(m0 + row) * K + k0 + sl * 8, (char*)Asl + c * 16);
      gl_lds16(Bt + (size_t)(n0 + row) * K + k0 + sl * 8, (char*)Bsl + c * 16);
    }
    __syncthreads();
    bf16x8 af[4], bfr[4];
#pragma unroll
    for (int i = 0; i < 4; ++i) {
      int ar = wr * 64 + i * 16 + (lane & 15);
      af[i] = *(const bf16x8*)&Asl[ar * 32 + (lane >> 4) * 8];
      int br = wc * 64 + i * 16 + (lane & 15);
      bfr[i] = *(const bf16x8*)&Bsl[br * 32 + (lane >> 4) * 8];
    }
#pragma unroll
    for (int i = 0; i < 4; ++i)
#pragma unroll
      for (int j = 0; j < 4; ++j)
        acc[i][j] = __builtin_amdgcn_mfma_f32_16x16x32_bf16(af[i], bfr[j],
                                                            acc[i][j], 0, 0, 0);
    __syncthreads();
  }

  int cg = lane >> 4, cc = lane & 15;
#pragma unroll
  for (int i = 0; i < 4; ++i) {
#pragma unroll
    for (int j = 0; j < 4; ++j) {
#pragma unroll
      for (int r = 0; r < 4; ++r) {
        int m = m0 + wr * 64 + i * 16 + cg * 4 + r;
        int n = n0 + wc * 64 + j * 16 + cc;
        float val = acc[i][j][r];
        if (MODE == 0) {
          val = (val + bias[n]) * 0.125f;  // fold 1/sqrt(Dh) into Q
          int b = m >> 11, s = m & 2047, h = n >> 6, dh = n & 63;
          ((u16*)Out)[((size_t)((b * SH + h) * SS + s) << 6) + dh] = f2bf(val);
        } else if (MODE == 1) {
          val += bias[n];
          int b = m >> 11, s = m & 2047, h = n >> 6, dh = n & 63;
          ((u16*)Out)[((size_t)((b * SH + h) * SS + s) << 6) + dh] = f2bf(val);
        } else if (MODE == 2) {
          val += bias[m];  // m is the 1024-dim here
          int h = m >> 6, dh = m & 63, b = n >> 11, s = n & 2047;
          ((u16*)Out)[((size_t)((b * SH + h) * SDH + dh) << 11) + s] = f2bf(val);
        } else {
          val += bias[n];
          ((float*)Out)[(size_t)m * N + n] = val;
        }
      }
    }
  }
}

// ---------------- attention -----------------------------------------
// grid: 64 (b,h) * 32 q-tiles. Block 256 thr = 4 waves, each wave 16 q rows.
// KV chunk = 64. K/V/P LDS tiles are [*][64]bf16 (128B rows) -> XOR swizzle
// byte ^= (row&7)<<4 on reads; staged via linear-dest global_load_lds with
// pre-swizzled SOURCE addresses (both-sides-or-neither rule).
__global__ __launch_bounds__(256, 2)
void attn_kernel(const u16* __restrict__ Qh, const u16* __restrict__ Kh,
                 const u16* __restrict__ Vt, const float* __restrict__ w,
                 u16* __restrict__ Ctx) {
  __shared__ u16 Kl[64 * 64];
  __shared__ u16 Vl[64 * 64];
  __shared__ u16 Pl[4][16 * 64];

  int bh = blockIdx.x >> 5;  // 0..63
  int qt = blockIdx.x & 31;
  int b = bh >> 4, h = bh & 15;
  int q0 = qt * 64;
  int tid = threadIdx.x, lane = tid & 63, wv = tid >> 6;
  const size_t basebh = (size_t)bh * SS * SDH;

  // Q fragments (Q was pre-scaled by 1/8 at projection)
  bf16x8 qf[2];
  int qrow = q0 + wv * 16 + (lane & 15);
#pragma unroll
  for (int ks = 0; ks < 2; ++ks)
    qf[ks] = *(const bf16x8*)&Qh[basebh + (size_t)qrow * SDH + ks * 32 +
                                 (lane >> 4) * 8];

  f32x4 ctx[4] = {};
  float rs[4] = {0.f, 0.f, 0.f, 0.f};
  const float* wb = w + b * SS;

  for (int kv0 = 0; kv0 < SS; kv0 += 64) {
#pragma unroll
    for (int it = 0; it < 2; ++it) {
      int c = tid + it * 256;            // 512 chunks of 16B
      int row = c >> 3, sl = c & 7;      // 8 x 16B per 128B row
      int ssl = sl ^ (row & 7);          // pre-swizzled source slot
      gl_lds16(Kh + basebh + (size_t)(kv0 + row) * SDH + ssl * 8,
               (char*)Kl + c * 16);
      gl_lds16(Vt + basebh + (size_t)row * SS + kv0 + ssl * 8,
               (char*)Vl + c * 16);
    }
    __syncthreads();

    // scores = Q K^T (scale already folded into Q)
    f32x4 sc[4] = {};
#pragma unroll
    for (int ct = 0; ct < 4; ++ct) {
#pragma unroll
      for (int ks = 0; ks < 2; ++ks) {
        int krow = ct * 16 + (lane & 15);
        int kel = ks * 32 + (lane >> 4) * 8;
        int byte = (krow * 128 + kel * 2) ^ ((krow & 7) << 4);
        bf16x8 kf = *(const bf16x8*)((const char*)Kl + byte);
        sc[ct] = __builtin_amdgcn_mfma_f32_16x16x32_bf16(qf[ks], kf, sc[ct],
                                                         0, 0, 0);
      }
    }

    // e = exp(score) * w[key]; accumulate row sums; stage P (bf16) in LDS
#pragma unroll
    for (int ct = 0; ct < 4; ++ct) {
      int col = ct * 16 + (lane & 15);
      float wcol = wb[kv0 + col];
#pragma unroll
      for (int r = 0; r < 4; ++r) {
        float e = __expf(sc[ct][r]) * wcol;
        rs[r] += e;
        int prow = (lane >> 4) * 4 + r;
        int byte = (prow * 128 + col * 2) ^ ((prow & 7) << 4);
        *(u16*)((char*)&Pl[wv][0] + byte) = f2bf(e);
      }
    }

    // ctx += P @ V  (per-wave P, same-wave LDS RAW handled by compiler)
#pragma unroll
    for (int nt = 0; nt < 4; ++nt) {
#pragma unroll
      for (int ks = 0; ks < 2; ++ks) {
        int kel = ks * 32 + (lane >> 4) * 8;
        int prow = lane & 15;
        int pbyte = (prow * 128 + kel * 2) ^ ((prow & 7) << 4);
        bf16x8 pf = *(const bf16x8*)((const char*)&Pl[wv][0] + pbyte);
        int vrow = nt * 16 + (lane & 15);
        int vbyte = (vrow * 128 + kel * 2) ^ ((vrow & 7) << 4);
        bf16x8 vf = *(const bf16x8*)((const char*)Vl + vbyte);
        ctx[nt] = __builtin_amdgcn_mfma_f32_16x16x32_bf16(pf, vf, ctx[nt],
                                                          0, 0, 0);
      }
    }
    __syncthreads();
  }

  // reduce row sums across the 16 lanes of each row group
#pragma unroll
  for (int r = 0; r < 4; ++r) {
    float vsum = rs[r];
    vsum += __shfl_xor(vsum, 1, 64);
    vsum += __shfl_xor(vsum, 2, 64);
    vsum += __shfl_xor(vsum, 4, 64);
    vsum += __shfl_xor(vsum, 8, 64);
    rs[r] = 1.0f / (vsum + 1e-12f);
  }

  // write context: Ctx[b][s][h*64+dh] (bf16)
#pragma unroll
  for (int nt = 0; nt < 4; ++nt) {
#pragma unroll
    for (int r = 0; r < 4; ++r) {
      int srow = q0 + wv * 16 + (lane >> 4) * 4 + r;
      int dh = nt * 16 + (lane & 15);
      float val = ctx[nt][r] * rs[r];
      Ctx[((size_t)(b * SS + srow) << 10) + h * SDH + dh] = f2bf(val);
    }
  }
}

extern "C" void kernel_launch(void* const* d_in, const int* in_sizes, int n_in,
                              void* d_out, int out_size, void* d_ws,
                              size_t ws_size, hipStream_t stream) {
  const float* q = (const float*)d_in[0];
  const float* k = (const float*)d_in[1];
  const float* v = (const float*)d_in[2];
  const float* w = (const float*)d_in[3];
  const float* Wq = (const float*)d_in[4];
  const float* bq = (const float*)d_in[5];
  const float* Wk = (const float*)d_in[6];
  const float* bk = (const float*)d_in[7];
  const float* Wv = (const float*)d_in[8];
  const float* bv = (const float*)d_in[9];
  const float* Wo = (const float*)d_in[10];
  const float* bo = (const float*)d_in[11];
  float* out = (float*)d_out;

  char* ws = (char*)d_ws;
  const size_t SZ = (size_t)8192 * 1024 * 2;  // one bf16 [8192][1024] buffer
  u16* qb = (u16*)(ws);
  u16* kb = (u16*)(ws + SZ);
  u16* vb = (u16*)(ws + 2 * SZ);
  u16* WqT = (u16*)(ws + 3 * SZ);
  u16* WkT = WqT + 1024 * 1024;
  u16* WvT = WkT + 1024 * 1024;
  u16* WoT = WvT + 1024 * 1024;
  u16* Qh = (u16*)(ws + 3 * SZ + (size_t)4 * 1024 * 1024 * 2);
  u16* Kh = Qh + (size_t)8192 * 1024;
  u16* Vt = Kh + (size_t)8192 * 1024;
  u16* Ctx = qb;  // qb is dead after the Q projection

  // 1) casts (8192*1024 elems each, 8 per thread)
  cast_bf16_kernel<<<4096, 256, 0, stream>>>(q, (u32*)qb, 1048576);
  cast_bf16_kernel<<<4096, 256, 0, stream>>>(k, (u32*)kb, 1048576);
  cast_bf16_kernel<<<4096, 256, 0, stream>>>(v, (u32*)vb, 1048576);

  // 2) weight transposes
  dim3 tb(32, 8), tg(32, 32);
  transpose_cast_kernel<<<tg, tb, 0, stream>>>(Wq, WqT);
  transpose_cast_kernel<<<tg, tb, 0, stream>>>(Wk, WkT);
  transpose_cast_kernel<<<tg, tb, 0, stream>>>(Wv, WvT);
  transpose_cast_kernel<<<tg, tb, 0, stream>>>(Wo, WoT);

  // 3) projections
  gemm_bt<0><<<512, 256, 0, stream>>>(qb, WqT, bq, Qh, 8192, 1024, 1024);
  gemm_bt<1><<<512, 256, 0, stream>>>(kb, WkT, bk, Kh, 8192, 1024, 1024);
  gemm_bt<2><<<512, 256, 0, stream>>>(WvT, vb, bv, Vt, 1024, 8192, 1024);

  // 4) attention
  attn_kernel<<<2048, 256, 0, stream>>>(Qh, Kh, Vt, w, Ctx);

  // 5) output projection (fp32 out + bias)
  gemm_bt<3><<<512, 256, 0, stream>>>(Ctx, WoT, bo, out, 8192, 1024, 1024);
}

// Round 2
// 254.379 us; speedup vs baseline: 1.0895x; 1.0895x over previous
//
#include <hip/hip_runtime.h>
#include <hip/hip_bf16.h>

typedef __bf16 bf16x8 __attribute__((ext_vector_type(8)));
typedef float f32x4 __attribute__((ext_vector_type(4)));
typedef float f32x16 __attribute__((ext_vector_type(16)));
typedef unsigned short u16;
typedef unsigned int u32;

// B=4, S=2048, D=1024, H=16, Dh=64
#define SB 4
#define SS 2048
#define SD 1024
#define SH 16
#define SDH 64

__device__ __forceinline__ u16 f2bf(float f) {
  union { float f; u32 u; } x; x.f = f;
  u32 r = (x.u + 0x7FFFu + ((x.u >> 16) & 1u)) >> 16;
  return (u16)r;
}

__device__ __forceinline__ void gl_lds16(const void* g, void* l) {
  __builtin_amdgcn_global_load_lds(
      (__attribute__((address_space(1))) void*)g,
      (__attribute__((address_space(3))) void*)l, 16, 0, 0);
}

// ---------------- cast fp32 -> bf16, 8 elems/thread ----------------
__global__ void cast_bf16_kernel(const float* __restrict__ in,
                                 u32* __restrict__ out, int n8) {
  int i = blockIdx.x * blockDim.x + threadIdx.x;
  if (i >= n8) return;
  const float4* inp = (const float4*)in;
  float4 a = inp[2 * i], b = inp[2 * i + 1];
  uint4 o;
  o.x = (u32)f2bf(a.x) | ((u32)f2bf(a.y) << 16);
  o.y = (u32)f2bf(a.z) | ((u32)f2bf(a.w) << 16);
  o.z = (u32)f2bf(b.x) | ((u32)f2bf(b.y) << 16);
  o.w = (u32)f2bf(b.z) | ((u32)f2bf(b.w) << 16);
  ((uint4*)out)[i] = o;
}

// ---------------- transpose + cast weight: Wt[n][k] = W[k][n] ------
__global__ void transpose_cast_kernel(const float* __restrict__ W,
                                      u16* __restrict__ Wt) {
  __shared__ float t[32][33];
  int bx = blockIdx.x, by = blockIdx.y;
  int tx = threadIdx.x, ty = threadIdx.y;  // 32 x 8
#pragma unroll
  for (int j = 0; j < 32; j += 8)
    t[ty + j][tx] = W[(size_t)(by * 32 + ty + j) * SD + bx * 32 + tx];
  __syncthreads();
#pragma unroll
  for (int j = 0; j < 32; j += 8)
    Wt[(size_t)(bx * 32 + ty + j) * SD + by * 32 + tx] = f2bf(t[tx][ty + j]);
}

// ---------------- GEMM: C[m][n] = sum_k A[m][k]*Bt[n][k] (+bias) ---
// 128x128 tile, BK=32, 256 thr = 4 waves (2x2), wave tile 64x64.
// MODE 0: out bf16 Qh[b][h][s][dh], scale 1/8   (bias[n])
// MODE 1: out bf16 Kh[b][h][s][dh]              (bias[n])
// MODE 2: out bf16 Vt[b][h][dh][s]  (A=WvT M=1024, Bt=vb N=8192, bias[m])
// MODE 3: out fp32 [m][n] (+bias[n])
template <int MODE>
__global__ __launch_bounds__(256, 2)
void gemm_bt(const u16* __restrict__ A, const u16* __restrict__ Bt,
             const float* __restrict__ bias, void* __restrict__ Out,
             int M, int N, int K) {
  __shared__ u16 Asl[128 * 32];
  __shared__ u16 Bsl[128 * 32];
  const int ntile = N >> 7;
  int bid = blockIdx.x;
  bid = (bid & 7) * ((int)gridDim.x >> 3) + (bid >> 3);  // XCD chunk swizzle
  int m0 = (bid / ntile) * 128, n0 = (bid % ntile) * 128;
  int tid = threadIdx.x;
  int lane = tid & 63, wv = tid >> 6;
  int wr = wv >> 1, wc = wv & 1;

  f32x4 acc[4][4] = {};

  for (int k0 = 0; k0 < K; k0 += 32) {
#pragma unroll
    for (int it = 0; it < 2; ++it) {
      int c = tid + it * 256;            // 512 chunks of 16B per tile
      int row = c >> 2, sl = c & 3;      // 4 x 16B per 64B row
      gl_lds16(A + (size_t)(m0 + row) * K + k0 + sl * 8, (char*)Asl + c * 16);
      gl_lds16(Bt + (size_t)(n0 + row) * K + k0 + sl * 8, (char*)Bsl + c * 16);
    }
    __syncthreads();
    bf16x8 af[4], bfr[4];
#pragma unroll
    for (int i = 0; i < 4; ++i) {
      int ar = wr * 64 + i * 16 + (lane & 15);
      af[i] = *(const bf16x8*)&Asl[ar * 32 + (lane >> 4) * 8];
      int br = wc * 64 + i * 16 + (lane & 15);
      bfr[i] = *(const bf16x8*)&Bsl[br * 32 + (lane >> 4) * 8];
    }
#pragma unroll
    for (int i = 0; i < 4; ++i)
#pragma unroll
      for (int j = 0; j < 4; ++j)
        acc[i][j] = __builtin_amdgcn_mfma_f32_16x16x32_bf16(af[i], bfr[j],
                                                            acc[i][j], 0, 0, 0);
    __syncthreads();
  }

  int cg = lane >> 4, cc = lane & 15;
#pragma unroll
  for (int i = 0; i < 4; ++i) {
#pragma unroll
    for (int j = 0; j < 4; ++j) {
#pragma unroll
      for (int r = 0; r < 4; ++r) {
        int m = m0 + wr * 64 + i * 16 + cg * 4 + r;
        int n = n0 + wc * 64 + j * 16 + cc;
        float val = acc[i][j][r];
        if (MODE == 0) {
          val = (val + bias[n]) * 0.125f;  // fold 1/sqrt(Dh) into Q
          int b = m >> 11, s = m & 2047, h = n >> 6, dh = n & 63;
          ((u16*)Out)[((size_t)((b * SH + h) * SS + s) << 6) + dh] = f2bf(val);
        } else if (MODE == 1) {
          val += bias[n];
          int b = m >> 11, s = m & 2047, h = n >> 6, dh = n & 63;
          ((u16*)Out)[((size_t)((b * SH + h) * SS + s) << 6) + dh] = f2bf(val);
        } else if (MODE == 2) {
          val += bias[m];  // m is the 1024-dim here
          int h = m >> 6, dh = m & 63, b = n >> 11, s = n & 2047;
          ((u16*)Out)[((size_t)((b * SH + h) * SDH + dh) << 11) + s] = f2bf(val);
        } else {
          val += bias[n];
          ((float*)Out)[(size_t)m * N + n] = val;
        }
      }
    }
  }
}

// ---------------- attention (swapped-QK^T, 32x32x16, in-reg softmax) ----
// grid: 1024 = 64 (b,h) * 16 q-tiles of 128 rows. Block 256 thr = 4 waves,
// each wave owns 32 q rows. KV chunk 64, double-buffered LDS.
// K/V LDS tiles [64][64]bf16, XOR swizzle byte^=(row&7)<<4, staged via
// pre-swizzled-source gl_lds (both-sides rule). Softmax in-register via
// swapped QK^T + cvt_pk_bf16 + permlane32_swap (T12).
__global__ __launch_bounds__(256, 3)
void attn_kernel(const u16* __restrict__ Qh, const u16* __restrict__ Kh,
                 const u16* __restrict__ Vt, const float* __restrict__ w,
                 u16* __restrict__ Ctx) {
  __shared__ u16 Kl[2][4096];
  __shared__ u16 Vl[2][4096];
  __shared__ float wl[SS];  // ln(w) for this batch row

  int bid = blockIdx.x;
  int swz = (bid & 7) * 128 + (bid >> 3);  // XCD chunk swizzle (1024 = 8*128)
  int bh = swz >> 4;                       // 0..63
  int qt = swz & 15;                       // 0..15
  int b = bh >> 4, hh = bh & 15;
  int q0 = qt * 128;
  int tid = threadIdx.x, lane = tid & 63, wv = tid >> 6;
  int ql = lane & 31, h = lane >> 5;
  const size_t basebh = (size_t)bh * (SS * SDH);

  auto stage = [&](int buf, int t) {
    int kv0 = t * 64;
#pragma unroll
    for (int it = 0; it < 2; ++it) {
      int c = tid + it * 256;          // 512 chunks of 16B
      int row = c >> 3, sl = c & 7;    // 8 x 16B per 128B row
      int ssl = sl ^ (row & 7);        // pre-swizzled source slot
      gl_lds16(Kh + basebh + (size_t)(kv0 + row) * SDH + ssl * 8,
               (char*)&Kl[buf][0] + c * 16);
      gl_lds16(Vt + basebh + (size_t)row * SS + kv0 + ssl * 8,
               (char*)&Vl[buf][0] + c * 16);
    }
  };

  stage(0, 0);

  // preload ln(w)
  const float* wb = w + b * SS;
  for (int i = tid; i < SS; i += 256) wl[i] = __logf(wb[i]);

  // Q fragments (B-operand of swapped QK^T): lane holds col q=ql,
  // dh elems st*16 + h*8 .. +8. Q pre-scaled by 1/8 at projection.
  bf16x8 qf[4];
  {
    const u16* qp = Qh + basebh + (size_t)(q0 + wv * 32 + ql) * SDH + h * 8;
#pragma unroll
    for (int st = 0; st < 4; ++st) qf[st] = *(const bf16x8*)(qp + st * 16);
  }

  f32x16 ctx0 = {}, ctx1 = {};
  float rs = 0.f;
  u32 pk[8][2];

  auto process = [&](const u16* Kb, const u16* Vb, int kv0) {
#pragma unroll
    for (int kt = 0; kt < 2; ++kt) {
      f32x16 sc = {};
      __builtin_amdgcn_s_setprio(1);
#pragma unroll
      for (int st = 0; st < 4; ++st) {
        int krow = kt * 32 + ql;
        int byt = (krow * 128 + (st * 16 + h * 8) * 2) ^ ((krow & 7) << 4);
        bf16x8 kf = *(const bf16x8*)((const char*)Kb + byt);
        sc = __builtin_amdgcn_mfma_f32_32x32x16_bf16(kf, qf[st], sc, 0, 0, 0);
      }
      __builtin_amdgcn_s_setprio(0);
      // lane holds P[q=ql][k = kv0 + 32kt + (reg&3) + 8*(reg>>2) + 4h]
#pragma unroll
      for (int e2 = 0; e2 < 4; ++e2) {
        float4 lw = *(const float4*)&wl[kv0 + kt * 32 + e2 * 8 + h * 4];
        float v0 = __expf(sc[e2 * 4 + 0] + lw.x);
        float v1 = __expf(sc[e2 * 4 + 1] + lw.y);
        float v2 = __expf(sc[e2 * 4 + 2] + lw.z);
        float v3 = __expf(sc[e2 * 4 + 3] + lw.w);
        rs += (v0 + v1) + (v2 + v3);
        u32 p0, p1;
        asm("v_cvt_pk_bf16_f32 %0, %1, %2" : "=v"(p0) : "v"(v0), "v"(v1));
        asm("v_cvt_pk_bf16_f32 %0, %1, %2" : "=v"(p1) : "v"(v2), "v"(v3));
        pk[kt * 4 + e2][0] = p0;  // P[q][8m+4h+{0,1}], m = 4kt+e2
        pk[kt * 4 + e2][1] = p1;  // P[q][8m+4h+{2,3}]
      }
    }
    // PV: for slice ksl, A-frag needs P[q][16ksl+8h..+8] = 8-block m=2ksl+h.
    // permlane32_swap pair (pk[2ksl], pk[2ksl+1]) delivers both halves.
#pragma unroll
    for (int ksl = 0; ksl < 4; ++ksl) {
      u32 d0 = pk[2 * ksl][0], d1 = pk[2 * ksl][1];
      u32 s0 = pk[2 * ksl + 1][0], s1 = pk[2 * ksl + 1][1];
      asm("v_permlane32_swap_b32 %0, %1" : "+v"(d0), "+v"(s0));
      asm("v_permlane32_swap_b32 %0, %1" : "+v"(d1), "+v"(s1));
      union { u32 u[4]; bf16x8 v; } pa;
      pa.u[0] = d0; pa.u[1] = d1; pa.u[2] = s0; pa.u[3] = s1;
      __builtin_amdgcn_s_setprio(1);
      {
        int byt0 = (ql * 128 + (ksl * 16 + h * 8) * 2) ^ ((ql & 7) << 4);
        bf16x8 vf0 = *(const bf16x8*)((const char*)Vb + byt0);
        ctx0 = __builtin_amdgcn_mfma_f32_32x32x16_bf16(pa.v, vf0, ctx0, 0, 0, 0);
        int vr1 = 32 + ql;
        int byt1 = (vr1 * 128 + (ksl * 16 + h * 8) * 2) ^ ((vr1 & 7) << 4);
        bf16x8 vf1 = *(const bf16x8*)((const char*)Vb + byt1);
        ctx1 = __builtin_amdgcn_mfma_f32_32x32x16_bf16(pa.v, vf1, ctx1, 0, 0, 0);
      }
      __builtin_amdgcn_s_setprio(0);
    }
  };

  for (int t = 0; t < 32; t += 2) {
    asm volatile("s_waitcnt vmcnt(0)" ::: "memory");
    __syncthreads();
    if (t + 1 < 32) stage(1, t + 1);
    process(&Kl[0][0], &Vl[0][0], t * 64);
    asm volatile("s_waitcnt vmcnt(0)" ::: "memory");
    __syncthreads();
    if (t + 2 < 32) stage(0, t + 2);
    process(&Kl[1][0], &Vl[1][0], (t + 1) * 64);
  }

  // denominator: lane holds partial sum for q=ql over its h-half of keys
  rs += __shfl_xor(rs, 32, 64);
  float rinv = 1.0f / (rs + 1e-12f);

  // write context: Ctx[b][s][hh*64+dh]; ctx row = (reg&3)+8*(reg>>2)+4h
#pragma unroll
  for (int reg = 0; reg < 16; ++reg) {
    int qrow = (reg & 3) + 8 * (reg >> 2) + 4 * h;
    float ri = __shfl(rinv, qrow, 64);
    int srow = q0 + wv * 32 + qrow;
    size_t base = ((size_t)(b * SS + srow) << 10) + hh * SDH;
    Ctx[base + ql] = f2bf(ctx0[reg] * ri);
    Ctx[base + 32 + ql] = f2bf(ctx1[reg] * ri);
  }
}

extern "C" void kernel_launch(void* const* d_in, const int* in_sizes, int n_in,
                              void* d_out, int out_size, void* d_ws,
                              size_t ws_size, hipStream_t stream) {
  const float* q = (const float*)d_in[0];
  const float* k = (const float*)d_in[1];
  const float* v = (const float*)d_in[2];
  const float* w = (const float*)d_in[3];
  const float* Wq = (const float*)d_in[4];
  const float* bq = (const float*)d_in[5];
  const float* Wk = (const float*)d_in[6];
  const float* bk = (const float*)d_in[7];
  const float* Wv = (const float*)d_in[8];
  const float* bv = (const float*)d_in[9];
  const float* Wo = (const float*)d_in[10];
  const float* bo = (const float*)d_in[11];
  float* out = (float*)d_out;

  char* ws = (char*)d_ws;
  const size_t SZ = (size_t)8192 * 1024 * 2;  // one bf16 [8192][1024] buffer
  u16* qb = (u16*)(ws);
  u16* kb = (u16*)(ws + SZ);
  u16* vb = (u16*)(ws + 2 * SZ);
  u16* WqT = (u16*)(ws + 3 * SZ);
  u16* WkT = WqT + 1024 * 1024;
  u16* WvT = WkT + 1024 * 1024;
  u16* WoT = WvT + 1024 * 1024;
  u16* Qh = (u16*)(ws + 3 * SZ + (size_t)4 * 1024 * 1024 * 2);
  u16* Kh = Qh + (size_t)8192 * 1024;
  u16* Vt = Kh + (size_t)8192 * 1024;
  u16* Ctx = qb;  // qb is dead after the Q projection

  // 1) casts (8192*1024 elems each, 8 per thread)
  cast_bf16_kernel<<<4096, 256, 0, stream>>>(q, (u32*)qb, 1048576);
  cast_bf16_kernel<<<4096, 256, 0, stream>>>(k, (u32*)kb, 1048576);
  cast_bf16_kernel<<<4096, 256, 0, stream>>>(v, (u32*)vb, 1048576);

  // 2) weight transposes
  dim3 tb(32, 8), tg(32, 32);
  transpose_cast_kernel<<<tg, tb, 0, stream>>>(Wq, WqT);
  transpose_cast_kernel<<<tg, tb, 0, stream>>>(Wk, WkT);
  transpose_cast_kernel<<<tg, tb, 0, stream>>>(Wv, WvT);
  transpose_cast_kernel<<<tg, tb, 0, stream>>>(Wo, WoT);

  // 3) projections
  gemm_bt<0><<<512, 256, 0, stream>>>(qb, WqT, bq, Qh, 8192, 1024, 1024);
  gemm_bt<1><<<512, 256, 0, stream>>>(kb, WkT, bk, Kh, 8192, 1024, 1024);
  gemm_bt<2><<<512, 256, 0, stream>>>(WvT, vb, bv, Vt, 1024, 8192, 1024);

  // 4) attention
  attn_kernel<<<1024, 256, 0, stream>>>(Qh, Kh, Vt, w, Ctx);

  // 5) output projection (fp32 out + bias)
  gemm_bt<3><<<512, 256, 0, stream>>>(Ctx, WoT, bo, out, 8192, 1024, 1024);
}

// Round 3
// 215.501 us; speedup vs baseline: 1.2861x; 1.1804x over previous
//
#include <hip/hip_runtime.h>
#include <hip/hip_bf16.h>

typedef __bf16 bf16x8 __attribute__((ext_vector_type(8)));
typedef float f32x4 __attribute__((ext_vector_type(4)));
typedef float f32x16 __attribute__((ext_vector_type(16)));
typedef unsigned short u16;
typedef unsigned int u32;

// B=4, S=2048, D=1024, H=16, Dh=64
#define SB 4
#define SS 2048
#define SD 1024
#define SH 16
#define SDH 64

__device__ __forceinline__ u16 f2bf(float f) {
  union { float f; u32 u; } x; x.f = f;
  u32 r = (x.u + 0x7FFFu + ((x.u >> 16) & 1u)) >> 16;
  return (u16)r;
}

__device__ __forceinline__ void gl_lds16(const void* g, void* l) {
  __builtin_amdgcn_global_load_lds(
      (__attribute__((address_space(1))) void*)g,
      (__attribute__((address_space(3))) void*)l, 16, 0, 0);
}

// ---------------- cast fp32 -> bf16, 8 elems/thread ----------------
__global__ void cast_bf16_kernel(const float* __restrict__ in,
                                 u32* __restrict__ out, int n8) {
  int i = blockIdx.x * blockDim.x + threadIdx.x;
  if (i >= n8) return;
  const float4* inp = (const float4*)in;
  float4 a = inp[2 * i], b = inp[2 * i + 1];
  uint4 o;
  o.x = (u32)f2bf(a.x) | ((u32)f2bf(a.y) << 16);
  o.y = (u32)f2bf(a.z) | ((u32)f2bf(a.w) << 16);
  o.z = (u32)f2bf(b.x) | ((u32)f2bf(b.y) << 16);
  o.w = (u32)f2bf(b.z) | ((u32)f2bf(b.w) << 16);
  ((uint4*)out)[i] = o;
}

// ---------------- transpose + cast weight: Wt[n][k] = W[k][n] ------
__global__ void transpose_cast_kernel(const float* __restrict__ W,
                                      u16* __restrict__ Wt) {
  __shared__ float t[32][33];
  int bx = blockIdx.x, by = blockIdx.y;
  int tx = threadIdx.x, ty = threadIdx.y;  // 32 x 8
#pragma unroll
  for (int j = 0; j < 32; j += 8)
    t[ty + j][tx] = W[(size_t)(by * 32 + ty + j) * SD + bx * 32 + tx];
  __syncthreads();
#pragma unroll
  for (int j = 0; j < 32; j += 8)
    Wt[(size_t)(bx * 32 + ty + j) * SD + by * 32 + tx] = f2bf(t[tx][ty + j]);
}

// ---------------- GEMM: C[m][n] = sum_k A[m][k]*Bt[n][k] (+bias) ---
// 128x128 tile, BK=64, double-buffered counted staging (T3-min),
// T2 XOR swizzle on LDS (byte ^= (row&7)<<4, pre-swizzled gl_lds source).
// MODE 0: out bf16 Qh[b][h][s][dh], scale log2e/8 (bias[n])
// MODE 1: out bf16 Kh[b][h][s][dh]               (bias[n])
// MODE 2: out bf16 Vt[b][h][dh][s]  (A=WvT M=1024, Bt=vb N=8192, bias[m])
// MODE 3: out fp32 [m][n] (+bias[n])
template <int MODE>
__global__ __launch_bounds__(256, 2)
void gemm_bt(const u16* __restrict__ A, const u16* __restrict__ Bt,
             const float* __restrict__ bias, void* __restrict__ Out,
             int M, int N, int K) {
  __shared__ u16 Asl[2][128 * 64];
  __shared__ u16 Bsl[2][128 * 64];
  const int ntile = N >> 7;
  int bid = blockIdx.x;
  bid = (bid & 7) * ((int)gridDim.x >> 3) + (bid >> 3);  // XCD chunk swizzle
  int m0 = (bid / ntile) * 128, n0 = (bid % ntile) * 128;
  int tid = threadIdx.x;
  int lane = tid & 63, wv = tid >> 6;
  int wr = wv >> 1, wc = wv & 1;

  auto stage = [&](int buf, int k0) {
#pragma unroll
    for (int it = 0; it < 4; ++it) {
      int c = tid + it * 256;            // 1024 chunks of 16B per matrix
      int row = c >> 3, sl = c & 7;      // 8 x 16B per 128B row
      int ssl = sl ^ (row & 7);          // pre-swizzled source slot
      gl_lds16(A + (size_t)(m0 + row) * K + k0 + ssl * 8,
               (char*)&Asl[buf][0] + c * 16);
      gl_lds16(Bt + (size_t)(n0 + row) * K + k0 + ssl * 8,
               (char*)&Bsl[buf][0] + c * 16);
    }
  };

  f32x4 acc[4][4] = {};
  stage(0, 0);
  asm volatile("s_waitcnt vmcnt(0)" ::: "memory");
  __syncthreads();

  int nk = K >> 6;
  for (int kt = 0; kt < nk; ++kt) {
    int buf = kt & 1;
    if (kt + 1 < nk) stage(buf ^ 1, (kt + 1) << 6);
#pragma unroll
    for (int kk = 0; kk < 2; ++kk) {
      bf16x8 af[4], bfr[4];
#pragma unroll
      for (int i = 0; i < 4; ++i) {
        int ar = wr * 64 + i * 16 + (lane & 15);
        int abyt = (ar * 128 + (kk * 32 + (lane >> 4) * 8) * 2) ^
                   ((ar & 7) << 4);
        af[i] = *(const bf16x8*)((const char*)&Asl[buf][0] + abyt);
        int br = wc * 64 + i * 16 + (lane & 15);
        int bbyt = (br * 128 + (kk * 32 + (lane >> 4) * 8) * 2) ^
                   ((br & 7) << 4);
        bfr[i] = *(const bf16x8*)((const char*)&Bsl[buf][0] + bbyt);
      }
#pragma unroll
      for (int i = 0; i < 4; ++i)
#pragma unroll
        for (int j = 0; j < 4; ++j)
          acc[i][j] = __builtin_amdgcn_mfma_f32_16x16x32_bf16(
              af[i], bfr[j], acc[i][j], 0, 0, 0);
    }
    asm volatile("s_waitcnt vmcnt(0)" ::: "memory");
    __syncthreads();
  }

  int cg = lane >> 4, cc = lane & 15;
#pragma unroll
  for (int i = 0; i < 4; ++i) {
#pragma unroll
    for (int j = 0; j < 4; ++j) {
#pragma unroll
      for (int r = 0; r < 4; ++r) {
        int m = m0 + wr * 64 + i * 16 + cg * 4 + r;
        int n = n0 + wc * 64 + j * 16 + cc;
        float val = acc[i][j][r];
        if (MODE == 0) {
          // fold (1/sqrt(Dh)) * log2(e) into Q for exp2-based softmax
          val = (val + bias[n]) * 0.18033688011112042f;
          int b = m >> 11, s = m & 2047, h = n >> 6, dh = n & 63;
          ((u16*)Out)[((size_t)((b * SH + h) * SS + s) << 6) + dh] = f2bf(val);
        } else if (MODE == 1) {
          val += bias[n];
          int b = m >> 11, s = m & 2047, h = n >> 6, dh = n & 63;
          ((u16*)Out)[((size_t)((b * SH + h) * SS + s) << 6) + dh] = f2bf(val);
        } else if (MODE == 2) {
          val += bias[m];  // m is the 1024-dim here
          int h = m >> 6, dh = m & 63, b = n >> 11, s = n & 2047;
          ((u16*)Out)[((size_t)((b * SH + h) * SDH + dh) << 11) + s] = f2bf(val);
        } else {
          val += bias[n];
          ((float*)Out)[(size_t)m * N + n] = val;
        }
      }
    }
  }
}

// ---------------- attention (swapped-QK^T, 32x32x16, in-reg softmax) ----
// grid: 512 = 64 (b,h) * 8 q-tiles of 256 rows. Block 256 thr = 4 waves,
// each wave owns 64 q rows (two 32-col B-fragments -> every K/V fragment
// feeds 2 MFMAs). KV chunk 128, double-buffered, processed in two 64-halves.
// Softmax: Q pre-scaled by log2e/8; accumulator C-in initialized with
// log2(w) so e = exp2(QK-acc) directly; P->bf16 via cvt_pk + permlane32.
__global__ __launch_bounds__(256, 2)
void attn_kernel(const u16* __restrict__ Qh, const u16* __restrict__ Kh,
                 const u16* __restrict__ Vt, const float* __restrict__ w,
                 u16* __restrict__ Ctx) {
  __shared__ u16 Kl[2][8192];   // [128 keys][64 dh], 128B rows, swizzled
  __shared__ u16 Vl[2][8192];   // [64 dh][128 keys], 256B rows, swizzled
  __shared__ float wl[SS];      // log2(w) for this batch row

  int bid = blockIdx.x;
  int swz = (bid & 7) * 64 + (bid >> 3);  // XCD chunk swizzle (512 = 8*64)
  int bh = swz >> 3;                      // 0..63
  int qt = swz & 7;                       // 0..7
  int b = bh >> 4, hh = bh & 15;
  int q0 = qt * 256;
  int tid = threadIdx.x, lane = tid & 63, wv = tid >> 6;
  int ql = lane & 31, h = lane >> 5;
  const size_t basebh = (size_t)bh * (SS * SDH);

  auto stage = [&](int buf, int t) {
    int kv0 = t * 128;
#pragma unroll
    for (int it = 0; it < 4; ++it) {
      int c = tid + it * 256;            // 1024 chunks of 16B each matrix
      int kr = c >> 3, ks = c & 7;       // K: 128 rows x 8 slots
      gl_lds16(Kh + basebh + (size_t)(kv0 + kr) * SDH + (ks ^ (kr & 7)) * 8,
               (char*)&Kl[buf][0] + c * 16);
      int vr = c >> 4, vs = c & 15;      // V: 64 rows x 16 slots
      gl_lds16(Vt + basebh + (size_t)vr * SS + kv0 + (vs ^ (vr & 7)) * 8,
               (char*)&Vl[buf][0] + c * 16);
    }
  };

  stage(0, 0);

  const float* wb = w + b * SS;
  for (int i = tid; i < SS; i += 256)
    wl[i] = __builtin_amdgcn_logf(wb[i]);  // v_log_f32 = log2

  // Q fragments (B-operand): q-block u covers cols q0+wv*64+u*32+ql
  bf16x8 qf[2][4];
#pragma unroll
  for (int u = 0; u < 2; ++u) {
    const u16* qp =
        Qh + basebh + (size_t)(q0 + wv * 64 + u * 32 + ql) * SDH + h * 8;
#pragma unroll
    for (int st = 0; st < 4; ++st) qf[u][st] = *(const bf16x8*)(qp + st * 16);
  }

  f32x16 ctx[2][2] = {};
  float rs[2] = {0.f, 0.f};

  asm volatile("s_waitcnt vmcnt(0)" ::: "memory");
  __syncthreads();

  for (int t = 0; t < 16; ++t) {
    int buf = t & 1;
    if (t + 1 < 16) stage(buf ^ 1, t + 1);
#pragma unroll
    for (int half = 0; half < 2; ++half) {
      const char* Kb = (const char*)&Kl[buf][half * 4096];
      const char* Vb = (const char*)&Vl[buf][0];
      int vc0 = half * 64;
      int kvb = t * 128 + half * 64;
      u32 pk[2][8][2];
#pragma unroll
      for (int kt = 0; kt < 2; ++kt) {
        bf16x8 kf[4];
#pragma unroll
        for (int st = 0; st < 4; ++st) {
          int krow = kt * 32 + ql;
          int byt = (krow * 128 + (st * 16 + h * 8) * 2) ^ ((krow & 7) << 4);
          kf[st] = *(const bf16x8*)(Kb + byt);
        }
        float4 lw[4];
#pragma unroll
        for (int e2 = 0; e2 < 4; ++e2)
          lw[e2] = *(const float4*)&wl[kvb + kt * 32 + e2 * 8 + h * 4];
#pragma unroll
        for (int u = 0; u < 2; ++u) {
          f32x16 sc;
#pragma unroll
          for (int e2 = 0; e2 < 4; ++e2) {
            sc[e2 * 4 + 0] = lw[e2].x;
            sc[e2 * 4 + 1] = lw[e2].y;
            sc[e2 * 4 + 2] = lw[e2].z;
            sc[e2 * 4 + 3] = lw[e2].w;
          }
          __builtin_amdgcn_s_setprio(1);
#pragma unroll
          for (int st = 0; st < 4; ++st)
            sc = __builtin_amdgcn_mfma_f32_32x32x16_bf16(kf[st], qf[u][st],
                                                         sc, 0, 0, 0);
          __builtin_amdgcn_s_setprio(0);
          // lane: P[q=ql][k = kvb + 32kt + (reg&3) + 8*(reg>>2) + 4h]
#pragma unroll
          for (int e2 = 0; e2 < 4; ++e2) {
            float v0 = __builtin_amdgcn_exp2f(sc[e2 * 4 + 0]);
            float v1 = __builtin_amdgcn_exp2f(sc[e2 * 4 + 1]);
            float v2 = __builtin_amdgcn_exp2f(sc[e2 * 4 + 2]);
            float v3 = __builtin_amdgcn_exp2f(sc[e2 * 4 + 3]);
            rs[u] += (v0 + v1) + (v2 + v3);
            u32 p0, p1;
            asm("v_cvt_pk_bf16_f32 %0, %1, %2" : "=v"(p0) : "v"(v0), "v"(v1));
            asm("v_cvt_pk_bf16_f32 %0, %1, %2" : "=v"(p1) : "v"(v2), "v"(v3));
            pk[u][kt * 4 + e2][0] = p0;
            pk[u][kt * 4 + e2][1] = p1;
          }
        }
      }
      // PV: V-frags shared by both q-blocks
#pragma unroll
      for (int ksl = 0; ksl < 4; ++ksl) {
        int cb = (vc0 + ksl * 16 + h * 8) * 2;
        int byt0 = (ql * 256 + cb) ^ ((ql & 7) << 4);
        bf16x8 vf0 = *(const bf16x8*)(Vb + byt0);
        int vr1 = 32 + ql;
        int byt1 = (vr1 * 256 + cb) ^ ((vr1 & 7) << 4);
        bf16x8 vf1 = *(const bf16x8*)(Vb + byt1);
#pragma unroll
        for (int u = 0; u < 2; ++u) {
          u32 d0 = pk[u][2 * ksl][0], d1 = pk[u][2 * ksl][1];
          u32 s0 = pk[u][2 * ksl + 1][0], s1 = pk[u][2 * ksl + 1][1];
          asm("v_permlane32_swap_b32 %0, %1" : "+v"(d0), "+v"(s0));
          asm("v_permlane32_swap_b32 %0, %1" : "+v"(d1), "+v"(s1));
          union { u32 uu[4]; bf16x8 v; } pa;
          pa.uu[0] = d0; pa.uu[1] = d1; pa.uu[2] = s0; pa.uu[3] = s1;
          __builtin_amdgcn_s_setprio(1);
          ctx[u][0] = __builtin_amdgcn_mfma_f32_32x32x16_bf16(
              pa.v, vf0, ctx[u][0], 0, 0, 0);
          ctx[u][1] = __builtin_amdgcn_mfma_f32_32x32x16_bf16(
              pa.v, vf1, ctx[u][1], 0, 0, 0);
          __builtin_amdgcn_s_setprio(0);
        }
      }
    }
    asm volatile("s_waitcnt vmcnt(0)" ::: "memory");
    __syncthreads();
  }

  // denominator + context write
#pragma unroll
  for (int u = 0; u < 2; ++u) {
    float rsu = rs[u];
    rsu += __shfl_xor(rsu, 32, 64);
    float rinv = 1.0f / (rsu + 1e-12f);
#pragma unroll
    for (int reg = 0; reg < 16; ++reg) {
      int qrow = (reg & 3) + 8 * (reg >> 2) + 4 * h;
      float ri = __shfl(rinv, qrow, 64);
      int srow = q0 + wv * 64 + u * 32 + qrow;
      size_t base = ((size_t)(b * SS + srow) << 10) + hh * SDH;
      Ctx[base + ql] = f2bf(ctx[u][0][reg] * ri);
      Ctx[base + 32 + ql] = f2bf(ctx[u][1][reg] * ri);
    }
  }
}

extern "C" void kernel_launch(void* const* d_in, const int* in_sizes, int n_in,
                              void* d_out, int out_size, void* d_ws,
                              size_t ws_size, hipStream_t stream) {
  const float* q = (const float*)d_in[0];
  const float* k = (const float*)d_in[1];
  const float* v = (const float*)d_in[2];
  const float* w = (const float*)d_in[3];
  const float* Wq = (const float*)d_in[4];
  const float* bq = (const float*)d_in[5];
  const float* Wk = (const float*)d_in[6];
  const float* bk = (const float*)d_in[7];
  const float* Wv = (const float*)d_in[8];
  const float* bv = (const float*)d_in[9];
  const float* Wo = (const float*)d_in[10];
  const float* bo = (const float*)d_in[11];
  float* out = (float*)d_out;

  char* ws = (char*)d_ws;
  const size_t SZ = (size_t)8192 * 1024 * 2;  // one bf16 [8192][1024] buffer
  u16* qb = (u16*)(ws);
  u16* kb = (u16*)(ws + SZ);
  u16* vb = (u16*)(ws + 2 * SZ);
  u16* WqT = (u16*)(ws + 3 * SZ);
  u16* WkT = WqT + 1024 * 1024;
  u16* WvT = WkT + 1024 * 1024;
  u16* WoT = WvT + 1024 * 1024;
  u16* Qh = (u16*)(ws + 3 * SZ + (size_t)4 * 1024 * 1024 * 2);
  u16* Kh = Qh + (size_t)8192 * 1024;
  u16* Vt = Kh + (size_t)8192 * 1024;
  u16* Ctx = qb;  // qb is dead after the Q projection

  // 1) casts (8192*1024 elems each, 8 per thread)
  cast_bf16_kernel<<<4096, 256, 0, stream>>>(q, (u32*)qb, 1048576);
  cast_bf16_kernel<<<4096, 256, 0, stream>>>(k, (u32*)kb, 1048576);
  cast_bf16_kernel<<<4096, 256, 0, stream>>>(v, (u32*)vb, 1048576);

  // 2) weight transposes
  dim3 tb(32, 8), tg(32, 32);
  transpose_cast_kernel<<<tg, tb, 0, stream>>>(Wq, WqT);
  transpose_cast_kernel<<<tg, tb, 0, stream>>>(Wk, WkT);
  transpose_cast_kernel<<<tg, tb, 0, stream>>>(Wv, WvT);
  transpose_cast_kernel<<<tg, tb, 0, stream>>>(Wo, WoT);

  // 3) projections
  gemm_bt<0><<<512, 256, 0, stream>>>(qb, WqT, bq, Qh, 8192, 1024, 1024);
  gemm_bt<1><<<512, 256, 0, stream>>>(kb, WkT, bk, Kh, 8192, 1024, 1024);
  gemm_bt<2><<<512, 256, 0, stream>>>(WvT, vb, bv, Vt, 1024, 8192, 1024);

  // 4) attention
  attn_kernel<<<512, 256, 0, stream>>>(Qh, Kh, Vt, w, Ctx);

  // 5) output projection (fp32 out + bias)
  gemm_bt<3><<<512, 256, 0, stream>>>(Ctx, WoT, bo, out, 8192, 1024, 1024);
}